// Round 16
// baseline (264.419 us; speedup 1.0000x reference)
//
#include <hip/hip_runtime.h>

#define FD 128            // feature dim
#define HD 64             // hidden per MLP
#define NC 128            // combined cols (64 MLP-a | 64 MLP-n)
#define RPB 64            // nodes per block (16 per wave)

typedef __attribute__((ext_vector_type(8))) short bf16x8;
typedef __attribute__((ext_vector_type(4))) float f32x4;

__device__ __forceinline__ unsigned bfr(float x) {
    unsigned u = __float_as_uint(x);
    return (u + 0x7fffu + ((u >> 16) & 1u)) >> 16;
}

__device__ __forceinline__ f32x4 ntload4(const float* p) {
    return __builtin_nontemporal_load(reinterpret_cast<const f32x4*>(p));
}

// Parallel prep: block n (0..127) = output col, thread f (0..127) = input feature.
__global__ __launch_bounds__(128) void prep_kernel(
    const float* __restrict__ lnag, const float* __restrict__ lnab,
    const float* __restrict__ Wa1, const float* __restrict__ ba1, const float* __restrict__ Wa2,
    const float* __restrict__ lnng, const float* __restrict__ lnnb,
    const float* __restrict__ Wn1, const float* __restrict__ bn1, const float* __restrict__ Wn2,
    unsigned short* __restrict__ wq, float* __restrict__ c, float* __restrict__ w2)
{
    int n = blockIdx.x;   // 0..127
    int f = threadIdx.x;  // 0..127
    const float* W  = (n < HD) ? Wa1 : Wn1;
    const float* g  = (n < HD) ? lnag : lnng;
    const float* bb = (n < HD) ? lnab : lnnb;
    const float* b1 = (n < HD) ? ba1 : bn1;
    const float* W2 = (n < HD) ? Wa2 : Wn2;
    int h = n & (HD - 1);
    float w = W[f * HD + h];
    wq[n * FD + f] = (unsigned short)bfr(g[f] * w);
    float partial = bb[f] * w;
#pragma unroll
    for (int off = 32; off; off >>= 1) partial += __shfl_xor(partial, off);
    __shared__ float ps[2];
    if ((f & 63) == 0) ps[f >> 6] = partial;
    __syncthreads();
    if (f == 0) { c[n] = ps[0] + ps[1] + b1[h]; w2[n] = W2[h]; }
}

// Segment starts from sorted batch_index (handles empty batches + sentinel).
__global__ __launch_bounds__(256) void bound_kernel(
    const int* __restrict__ bidx, int* __restrict__ start, int n_nodes, int n_batch)
{
    int i = (int)(blockIdx.x * blockDim.x + threadIdx.x);
    if (i >= n_nodes) return;
    int b = bidx[i];
    if (i == 0) {
        for (int x = 0; x <= b; ++x) start[x] = 0;
    } else {
        int pb = bidx[i - 1];
        for (int x = pb + 1; x <= b; ++x) start[x] = i;
    }
    if (i == n_nodes - 1) {
        for (int x = b + 1; x <= n_batch; ++x) start[x] = n_nodes;
    }
}

// R15 fused kernel, one change: __launch_bounds__(256, 6) -> VGPR cap ~84, 24 waves/CU.
__global__ __launch_bounds__(256, 6) void fused_kernel(
    const float* __restrict__ scaler, const float* __restrict__ vec,
    const float* __restrict__ wnu, const float* __restrict__ pos,
    const float* __restrict__ mc, const int* __restrict__ bidx,
    const unsigned short* __restrict__ wq, const float* __restrict__ c,
    const float* __restrict__ w2, const float* __restrict__ ba2,
    const float* __restrict__ bn2, float* __restrict__ val, int n_nodes)
{
    __shared__ float tl[4][16];      // per-wave t strip

    int tid = threadIdx.x;
    int lane = tid & 63, w = tid >> 6;
    int rowbase = blockIdx.x * RPB + w * 16;   // this wave's 16 nodes
    int lrow = lane & 15, lgrp = lane >> 4;

    // ---- X loads first (straight into A-fragment registers, nontemporal) ----
    int xnode = rowbase + lrow;
    int gx = xnode < n_nodes ? xnode : (n_nodes - 1);
    const float* xp = scaler + (size_t)gx * FD;
    f32x4 xv[8];
#pragma unroll
    for (int ks = 0; ks < 4; ++ks) {
        xv[2 * ks]     = ntload4(xp + (ks * 8 + lgrp * 2) * 4);
        xv[2 * ks + 1] = ntload4(xp + (ks * 8 + lgrp * 2 + 1) * 4);
    }

    // ---- T phase: 8 lanes per node, nontemporal vec stream ----
    {
        int o = lane >> 3, cc = lane & 7;
        f32x4 wn4[4];
#pragma unroll
        for (int m = 0; m < 4; ++m)
            wn4[m] = *reinterpret_cast<const f32x4*>(wnu + (m * 8 + cc) * 4);
#pragma unroll
        for (int g = 0; g < 2; ++g) {
            int row = g * 8 + o;
            int node = rowbase + row;
            int n = node < n_nodes ? node : (n_nodes - 1);
            int b = bidx[n];
            float m0 = pos[n * 3 + 0] - mc[b * 3 + 0];
            float m1 = pos[n * 3 + 1] - mc[b * 3 + 1];
            float m2 = pos[n * 3 + 2] - mc[b * 3 + 2];
            const float* vr = vec + (size_t)n * 3 * FD;
            float acc = 0.f;
#pragma unroll
            for (int k = 0; k < 12; ++k) {
                f32x4 v = ntload4(vr + (cc + k * 8) * 4);
                f32x4 wnv = wn4[k & 3];
                float d4 = v.x * wnv.x + v.y * wnv.y + v.z * wnv.z + v.w * wnv.w;
                float mm = (k < 4) ? m0 : (k < 8 ? m1 : m2);
                acc = fmaf(d4, mm, acc);
            }
            acc += __shfl_xor(acc, 1);
            acc += __shfl_xor(acc, 2);
            acc += __shfl_xor(acc, 4);
            if (cc == 0) tl[w][row] = acc;
        }
    }

    // ---- LN in-register: reduce over the 4 lanes sharing this row ----
    float s = 0.f, s2 = 0.f;
#pragma unroll
    for (int i = 0; i < 8; ++i) {
        f32x4 v = xv[i];
        s  += v.x + v.y + v.z + v.w;
        s2 += v.x * v.x + v.y * v.y + v.z * v.z + v.w * v.w;
    }
    s  += __shfl_xor(s, 16);  s  += __shfl_xor(s, 32);
    s2 += __shfl_xor(s2, 16); s2 += __shfl_xor(s2, 32);
    float mu = s * (1.f / FD);
    float var = s2 * (1.f / FD) - mu * mu;
    float rstd = rsqrtf(var + 1e-5f);

    bf16x8 af[4];
#pragma unroll
    for (int ks = 0; ks < 4; ++ks) {
        f32x4 a = xv[2 * ks], b = xv[2 * ks + 1];
        union { unsigned u[4]; bf16x8 v; } pk;
        pk.u[0] = bfr((a.x - mu) * rstd) | (bfr((a.y - mu) * rstd) << 16);
        pk.u[1] = bfr((a.z - mu) * rstd) | (bfr((a.w - mu) * rstd) << 16);
        pk.u[2] = bfr((b.x - mu) * rstd) | (bfr((b.y - mu) * rstd) << 16);
        pk.u[3] = bfr((b.z - mu) * rstd) | (bfr((b.w - mu) * rstd) << 16);
        af[ks] = pk.v;
    }

    // ---- MFMA: 16 rows x 128 cols, K=128; tiles paired (2 indep chains in flight) ----
    float pa[4] = {0.f, 0.f, 0.f, 0.f}, pn[4] = {0.f, 0.f, 0.f, 0.f};
#pragma unroll
    for (int tp = 0; tp < 4; ++tp) {
        f32x4 a0 = {0.f, 0.f, 0.f, 0.f}, a1 = {0.f, 0.f, 0.f, 0.f};
        int n0 = (2 * tp) * 16 + lrow, n1 = (2 * tp + 1) * 16 + lrow;
        const bf16x8* brow0 = reinterpret_cast<const bf16x8*>(wq + n0 * FD);
        const bf16x8* brow1 = reinterpret_cast<const bf16x8*>(wq + n1 * FD);
#pragma unroll
        for (int ks = 0; ks < 4; ++ks) {
            bf16x8 bf0 = brow0[ks * 4 + lgrp];
            bf16x8 bf1 = brow1[ks * 4 + lgrp];
            a0 = __builtin_amdgcn_mfma_f32_16x16x32_bf16(af[ks], bf0, a0, 0, 0, 0);
            a1 = __builtin_amdgcn_mfma_f32_16x16x32_bf16(af[ks], bf1, a1, 0, 0, 0);
        }
#pragma unroll
        for (int half = 0; half < 2; ++half) {
            f32x4 acc = half ? a1 : a0;
            int tc = 2 * tp + half;
            int col = tc * 16 + lrow;
            float bias = c[col], w2v = w2[col];
#pragma unroll
            for (int r = 0; r < 4; ++r) {
                float h1 = acc[r] + bias;
                float y = h1 / (1.f + __expf(-h1));
                float cb = y * w2v;
                if (tc < 4) pa[r] += cb; else pn[r] += cb;
            }
        }
    }
#pragma unroll
    for (int off = 1; off < 16; off <<= 1) {
#pragma unroll
        for (int r = 0; r < 4; ++r) {
            pa[r] += __shfl_xor(pa[r], off);
            pn[r] += __shfl_xor(pn[r], off);
        }
    }
    if (lrow == 0) {
        float b2a = ba2[0], b2n = bn2[0];
        float tmp[4];
#pragma unroll
        for (int r = 0; r < 4; ++r) {
            int nl = lgrp * 4 + r;
            tmp[r] = (pa[r] + b2a) + (2.f / 3.f) * (pn[r] + b2n) * tl[w][nl];
        }
        int node0 = rowbase + lgrp * 4;
        if (node0 + 3 < n_nodes) {
            f32x4 o4 = {tmp[0], tmp[1], tmp[2], tmp[3]};
            *reinterpret_cast<f32x4*>(val + node0) = o4;
        } else {
#pragma unroll
            for (int r = 0; r < 4; ++r)
                if (node0 + r < n_nodes) val[node0 + r] = tmp[r];
        }
    }
}

// One thread per batch: start table + 4 independent accumulator chains.
__global__ __launch_bounds__(256) void reduce_kernel(
    const float* __restrict__ val, const int* __restrict__ start,
    float* __restrict__ out, int n_batch)
{
    int b = (int)(blockIdx.x * blockDim.x + threadIdx.x);
    if (b >= n_batch) return;
    int i = start[b], e = start[b + 1];
    float a0 = 0.f, a1 = 0.f, a2 = 0.f, a3 = 0.f;
    for (; i + 4 <= e; i += 4) {
        a0 += val[i]; a1 += val[i + 1]; a2 += val[i + 2]; a3 += val[i + 3];
    }
    for (; i < e; ++i) a0 += val[i];
    out[b] = (a0 + a1) + (a2 + a3);
}

extern "C" void kernel_launch(void* const* d_in, const int* in_sizes, int n_in,
                              void* d_out, int out_size, void* d_ws, size_t ws_size,
                              hipStream_t stream) {
    const float* pos    = (const float*)d_in[0];
    const float* mc     = (const float*)d_in[1];
    const float* scaler = (const float*)d_in[2];
    const float* vec    = (const float*)d_in[3];
    const int*   bidx   = (const int*)d_in[4];
    const float* lnag   = (const float*)d_in[5];
    const float* lnab   = (const float*)d_in[6];
    const float* Wa1    = (const float*)d_in[7];
    const float* ba1    = (const float*)d_in[8];
    const float* Wa2    = (const float*)d_in[9];
    const float* ba2    = (const float*)d_in[10];
    const float* lnng   = (const float*)d_in[11];
    const float* lnnb   = (const float*)d_in[12];
    const float* Wn1    = (const float*)d_in[13];
    const float* bn1    = (const float*)d_in[14];
    const float* Wn2    = (const float*)d_in[15];
    const float* bn2    = (const float*)d_in[16];
    const float* Wnu    = (const float*)d_in[17];

    int N = in_sizes[0] / 3;
    int B = in_sizes[1] / 3;

    unsigned short* wq = (unsigned short*)d_ws;            // NC*FD bf16 = 32 KiB
    float* c  = (float*)((char*)d_ws + NC * FD * 2);       // 128 f32
    float* w2 = c + NC;                                    // 128 f32
    float* val = w2 + NC;                                  // N f32
    int* start = (int*)(val + N);                          // B+1 ints

    hipLaunchKernelGGL(prep_kernel, dim3(NC), dim3(FD), 0, stream,
                       lnag, lnab, Wa1, ba1, Wa2, lnng, lnnb, Wn1, bn1, Wn2, wq, c, w2);

    int bblocks = (N + 255) / 256;
    hipLaunchKernelGGL(bound_kernel, dim3(bblocks), dim3(256), 0, stream,
                       bidx, start, N, B);

    int blocks = (N + RPB - 1) / RPB;
    hipLaunchKernelGGL(fused_kernel, dim3(blocks), dim3(256), 0, stream,
                       scaler, vec, Wnu, pos, mc, bidx, wq, c, w2, ba2, bn2,
                       val, N);

    int rblocks = (B + 255) / 256;
    hipLaunchKernelGGL(reduce_kernel, dim3(rblocks), dim3(256), 0, stream,
                       val, start, (float*)d_out, B);
}

// Round 17
// 221.961 us; speedup vs baseline: 1.1913x; 1.1913x over previous
//
#include <hip/hip_runtime.h>

#define FD 128            // feature dim
#define HD 64             // hidden per MLP
#define NC 128            // combined cols (64 MLP-a | 64 MLP-n)
#define RPB 64            // nodes per block (16 per wave)

typedef __attribute__((ext_vector_type(8))) short bf16x8;
typedef __attribute__((ext_vector_type(4))) float f32x4;

__device__ __forceinline__ unsigned bfr(float x) {
    unsigned u = __float_as_uint(x);
    return (u + 0x7fffu + ((u >> 16) & 1u)) >> 16;
}

__device__ __forceinline__ f32x4 ntload4(const float* p) {
    return __builtin_nontemporal_load(reinterpret_cast<const f32x4*>(p));
}

// Parallel prep: block n (0..127) = output col, thread f (0..127) = input feature.
__global__ __launch_bounds__(128) void prep_kernel(
    const float* __restrict__ lnag, const float* __restrict__ lnab,
    const float* __restrict__ Wa1, const float* __restrict__ ba1, const float* __restrict__ Wa2,
    const float* __restrict__ lnng, const float* __restrict__ lnnb,
    const float* __restrict__ Wn1, const float* __restrict__ bn1, const float* __restrict__ Wn2,
    unsigned short* __restrict__ wq, float* __restrict__ c, float* __restrict__ w2)
{
    int n = blockIdx.x;   // 0..127
    int f = threadIdx.x;  // 0..127
    const float* W  = (n < HD) ? Wa1 : Wn1;
    const float* g  = (n < HD) ? lnag : lnng;
    const float* bb = (n < HD) ? lnab : lnnb;
    const float* b1 = (n < HD) ? ba1 : bn1;
    const float* W2 = (n < HD) ? Wa2 : Wn2;
    int h = n & (HD - 1);
    float w = W[f * HD + h];
    wq[n * FD + f] = (unsigned short)bfr(g[f] * w);
    float partial = bb[f] * w;
#pragma unroll
    for (int off = 32; off; off >>= 1) partial += __shfl_xor(partial, off);
    __shared__ float ps[2];
    if ((f & 63) == 0) ps[f >> 6] = partial;
    __syncthreads();
    if (f == 0) { c[n] = ps[0] + ps[1] + b1[h]; w2[n] = W2[h]; }
}

// Segment starts from sorted batch_index (handles empty batches + sentinel).
__global__ __launch_bounds__(256) void bound_kernel(
    const int* __restrict__ bidx, int* __restrict__ start, int n_nodes, int n_batch)
{
    int i = (int)(blockIdx.x * blockDim.x + threadIdx.x);
    if (i >= n_nodes) return;
    int b = bidx[i];
    if (i == 0) {
        for (int x = 0; x <= b; ++x) start[x] = 0;
    } else {
        int pb = bidx[i - 1];
        for (int x = pb + 1; x <= b; ++x) start[x] = i;
    }
    if (i == n_nodes - 1) {
        for (int x = b + 1; x <= n_batch; ++x) start[x] = n_nodes;
    }
}

// R15 fused kernel (best): barrier-free, 16 nodes/wave, nontemporal streams,
// in-register LN, MFMA with 2-wide tile pairing, coalesced val store.
__global__ __launch_bounds__(256, 4) void fused_kernel(
    const float* __restrict__ scaler, const float* __restrict__ vec,
    const float* __restrict__ wnu, const float* __restrict__ pos,
    const float* __restrict__ mc, const int* __restrict__ bidx,
    const unsigned short* __restrict__ wq, const float* __restrict__ c,
    const float* __restrict__ w2, const float* __restrict__ ba2,
    const float* __restrict__ bn2, float* __restrict__ val, int n_nodes)
{
    __shared__ float tl[4][16];      // per-wave t strip

    int tid = threadIdx.x;
    int lane = tid & 63, w = tid >> 6;
    int rowbase = blockIdx.x * RPB + w * 16;   // this wave's 16 nodes
    int lrow = lane & 15, lgrp = lane >> 4;

    // ---- X loads first (straight into A-fragment registers, nontemporal) ----
    int xnode = rowbase + lrow;
    int gx = xnode < n_nodes ? xnode : (n_nodes - 1);
    const float* xp = scaler + (size_t)gx * FD;
    f32x4 xv[8];
#pragma unroll
    for (int ks = 0; ks < 4; ++ks) {
        xv[2 * ks]     = ntload4(xp + (ks * 8 + lgrp * 2) * 4);
        xv[2 * ks + 1] = ntload4(xp + (ks * 8 + lgrp * 2 + 1) * 4);
    }

    // ---- T phase: 8 lanes per node, nontemporal vec stream ----
    {
        int o = lane >> 3, cc = lane & 7;
        f32x4 wn4[4];
#pragma unroll
        for (int m = 0; m < 4; ++m)
            wn4[m] = *reinterpret_cast<const f32x4*>(wnu + (m * 8 + cc) * 4);
#pragma unroll
        for (int g = 0; g < 2; ++g) {
            int row = g * 8 + o;
            int node = rowbase + row;
            int n = node < n_nodes ? node : (n_nodes - 1);
            int b = bidx[n];
            float m0 = pos[n * 3 + 0] - mc[b * 3 + 0];
            float m1 = pos[n * 3 + 1] - mc[b * 3 + 1];
            float m2 = pos[n * 3 + 2] - mc[b * 3 + 2];
            const float* vr = vec + (size_t)n * 3 * FD;
            float acc = 0.f;
#pragma unroll
            for (int k = 0; k < 12; ++k) {
                f32x4 v = ntload4(vr + (cc + k * 8) * 4);
                f32x4 wnv = wn4[k & 3];
                float d4 = v.x * wnv.x + v.y * wnv.y + v.z * wnv.z + v.w * wnv.w;
                float mm = (k < 4) ? m0 : (k < 8 ? m1 : m2);
                acc = fmaf(d4, mm, acc);
            }
            acc += __shfl_xor(acc, 1);
            acc += __shfl_xor(acc, 2);
            acc += __shfl_xor(acc, 4);
            if (cc == 0) tl[w][row] = acc;
        }
    }

    // ---- LN in-register: reduce over the 4 lanes sharing this row ----
    float s = 0.f, s2 = 0.f;
#pragma unroll
    for (int i = 0; i < 8; ++i) {
        f32x4 v = xv[i];
        s  += v.x + v.y + v.z + v.w;
        s2 += v.x * v.x + v.y * v.y + v.z * v.z + v.w * v.w;
    }
    s  += __shfl_xor(s, 16);  s  += __shfl_xor(s, 32);
    s2 += __shfl_xor(s2, 16); s2 += __shfl_xor(s2, 32);
    float mu = s * (1.f / FD);
    float var = s2 * (1.f / FD) - mu * mu;
    float rstd = rsqrtf(var + 1e-5f);

    bf16x8 af[4];
#pragma unroll
    for (int ks = 0; ks < 4; ++ks) {
        f32x4 a = xv[2 * ks], b = xv[2 * ks + 1];
        union { unsigned u[4]; bf16x8 v; } pk;
        pk.u[0] = bfr((a.x - mu) * rstd) | (bfr((a.y - mu) * rstd) << 16);
        pk.u[1] = bfr((a.z - mu) * rstd) | (bfr((a.w - mu) * rstd) << 16);
        pk.u[2] = bfr((b.x - mu) * rstd) | (bfr((b.y - mu) * rstd) << 16);
        pk.u[3] = bfr((b.z - mu) * rstd) | (bfr((b.w - mu) * rstd) << 16);
        af[ks] = pk.v;
    }

    // ---- MFMA: 16 rows x 128 cols, K=128; tiles paired (2 indep chains in flight) ----
    float pa[4] = {0.f, 0.f, 0.f, 0.f}, pn[4] = {0.f, 0.f, 0.f, 0.f};
#pragma unroll
    for (int tp = 0; tp < 4; ++tp) {
        f32x4 a0 = {0.f, 0.f, 0.f, 0.f}, a1 = {0.f, 0.f, 0.f, 0.f};
        int n0 = (2 * tp) * 16 + lrow, n1 = (2 * tp + 1) * 16 + lrow;
        const bf16x8* brow0 = reinterpret_cast<const bf16x8*>(wq + n0 * FD);
        const bf16x8* brow1 = reinterpret_cast<const bf16x8*>(wq + n1 * FD);
#pragma unroll
        for (int ks = 0; ks < 4; ++ks) {
            bf16x8 bf0 = brow0[ks * 4 + lgrp];
            bf16x8 bf1 = brow1[ks * 4 + lgrp];
            a0 = __builtin_amdgcn_mfma_f32_16x16x32_bf16(af[ks], bf0, a0, 0, 0, 0);
            a1 = __builtin_amdgcn_mfma_f32_16x16x32_bf16(af[ks], bf1, a1, 0, 0, 0);
        }
#pragma unroll
        for (int half = 0; half < 2; ++half) {
            f32x4 acc = half ? a1 : a0;
            int tc = 2 * tp + half;
            int col = tc * 16 + lrow;
            float bias = c[col], w2v = w2[col];
#pragma unroll
            for (int r = 0; r < 4; ++r) {
                float h1 = acc[r] + bias;
                float y = h1 / (1.f + __expf(-h1));
                float cb = y * w2v;
                if (tc < 4) pa[r] += cb; else pn[r] += cb;
            }
        }
    }
#pragma unroll
    for (int off = 1; off < 16; off <<= 1) {
#pragma unroll
        for (int r = 0; r < 4; ++r) {
            pa[r] += __shfl_xor(pa[r], off);
            pn[r] += __shfl_xor(pn[r], off);
        }
    }
    if (lrow == 0) {
        float b2a = ba2[0], b2n = bn2[0];
        float tmp[4];
#pragma unroll
        for (int r = 0; r < 4; ++r) {
            int nl = lgrp * 4 + r;
            tmp[r] = (pa[r] + b2a) + (2.f / 3.f) * (pn[r] + b2n) * tl[w][nl];
        }
        int node0 = rowbase + lgrp * 4;
        if (node0 + 3 < n_nodes) {
            f32x4 o4 = {tmp[0], tmp[1], tmp[2], tmp[3]};
            *reinterpret_cast<f32x4*>(val + node0) = o4;
        } else {
#pragma unroll
            for (int r = 0; r < 4; ++r)
                if (node0 + r < n_nodes) val[node0 + r] = tmp[r];
        }
    }
}

// One thread per batch: start table + 4 independent accumulator chains.
__global__ __launch_bounds__(256) void reduce_kernel(
    const float* __restrict__ val, const int* __restrict__ start,
    float* __restrict__ out, int n_batch)
{
    int b = (int)(blockIdx.x * blockDim.x + threadIdx.x);
    if (b >= n_batch) return;
    int i = start[b], e = start[b + 1];
    float a0 = 0.f, a1 = 0.f, a2 = 0.f, a3 = 0.f;
    for (; i + 4 <= e; i += 4) {
        a0 += val[i]; a1 += val[i + 1]; a2 += val[i + 2]; a3 += val[i + 3];
    }
    for (; i < e; ++i) a0 += val[i];
    out[b] = (a0 + a1) + (a2 + a3);
}

extern "C" void kernel_launch(void* const* d_in, const int* in_sizes, int n_in,
                              void* d_out, int out_size, void* d_ws, size_t ws_size,
                              hipStream_t stream) {
    const float* pos    = (const float*)d_in[0];
    const float* mc     = (const float*)d_in[1];
    const float* scaler = (const float*)d_in[2];
    const float* vec    = (const float*)d_in[3];
    const int*   bidx   = (const int*)d_in[4];
    const float* lnag   = (const float*)d_in[5];
    const float* lnab   = (const float*)d_in[6];
    const float* Wa1    = (const float*)d_in[7];
    const float* ba1    = (const float*)d_in[8];
    const float* Wa2    = (const float*)d_in[9];
    const float* ba2    = (const float*)d_in[10];
    const float* lnng   = (const float*)d_in[11];
    const float* lnnb   = (const float*)d_in[12];
    const float* Wn1    = (const float*)d_in[13];
    const float* bn1    = (const float*)d_in[14];
    const float* Wn2    = (const float*)d_in[15];
    const float* bn2    = (const float*)d_in[16];
    const float* Wnu    = (const float*)d_in[17];

    int N = in_sizes[0] / 3;
    int B = in_sizes[1] / 3;

    unsigned short* wq = (unsigned short*)d_ws;            // NC*FD bf16 = 32 KiB
    float* c  = (float*)((char*)d_ws + NC * FD * 2);       // 128 f32
    float* w2 = c + NC;                                    // 128 f32
    float* val = w2 + NC;                                  // N f32
    int* start = (int*)(val + N);                          // B+1 ints

    hipLaunchKernelGGL(prep_kernel, dim3(NC), dim3(FD), 0, stream,
                       lnag, lnab, Wa1, ba1, Wa2, lnng, lnnb, Wn1, bn1, Wn2, wq, c, w2);

    int bblocks = (N + 255) / 256;
    hipLaunchKernelGGL(bound_kernel, dim3(bblocks), dim3(256), 0, stream,
                       bidx, start, N, B);

    int blocks = (N + RPB - 1) / RPB;
    hipLaunchKernelGGL(fused_kernel, dim3(blocks), dim3(256), 0, stream,
                       scaler, vec, Wnu, pos, mc, bidx, wq, c, w2, ba2, bn2,
                       val, N);

    int rblocks = (B + 255) / 256;
    hipLaunchKernelGGL(reduce_kernel, dim3(rblocks), dim3(256), 0, stream,
                       val, start, (float*)d_out, B);
}